// Round 1
// baseline (487.271 us; speedup 1.0000x reference)
//
#include <hip/hip_runtime.h>
#include <hip/hip_bf16.h>

typedef unsigned short u16;
typedef unsigned long long u64;
typedef __attribute__((ext_vector_type(8))) short short8;
typedef __attribute__((ext_vector_type(4))) float f32x4;

#define NB 64
#define NP 256
#define NE 256
#define NH 8
#define NHD 32
#define NU 6
#define NDFF 1024
#define NM (NB*NP)   // 16384 tokens

__device__ __forceinline__ u16 f2bf(float f) {
  unsigned u = __float_as_uint(f);
  unsigned r = 0x7fffu + ((u >> 16) & 1u);
  return (u16)((u + r) >> 16);
}

// ---------------- K0: transpose weights to bf16 (B^T layouts for MFMA) ----
__global__ __launch_bounds__(256) void k_prep(
    const float* __restrict__ wq, const float* __restrict__ wk, const float* __restrict__ wv,
    const float* __restrict__ wo, const float* __restrict__ w1, const float* __restrict__ w2,
    u16* __restrict__ wqkvT, u16* __restrict__ woT, u16* __restrict__ w1T, u16* __restrict__ w2T) {
  int tid = blockIdx.x * 256 + threadIdx.x;
  int stride = gridDim.x * 256;
  for (int i = tid; i < 768 * 256; i += stride) {
    int n = i >> 8, kk = i & 255;
    const float* s = (n < 256) ? wq : ((n < 512) ? wk : wv);
    wqkvT[i] = f2bf(s[kk * 256 + (n & 255)]);
  }
  for (int i = tid; i < 256 * 256; i += stride)  { int n = i >> 8,  kk = i & 255;  woT[i] = f2bf(wo[kk * 256 + n]); }
  for (int i = tid; i < 1024 * 256; i += stride) { int n = i >> 8,  kk = i & 255;  w1T[i] = f2bf(w1[kk * 1024 + n]); }
  for (int i = tid; i < 256 * 1024; i += stride) { int n = i >> 10, kk = i & 1023; w2T[i] = f2bf(w2[kk * 256 + n]); }
}

// ---------------- K1: LayerNorm1 -> xn bf16 [16384][256] --------------------
__global__ __launch_bounds__(256) void k_ln1(
    const float* __restrict__ x, const float* __restrict__ w, const float* __restrict__ b,
    u16* __restrict__ xn) {
  int row = blockIdx.x * 4 + (threadIdx.x >> 6);
  int lane = threadIdx.x & 63;
  const float* xr = x + (size_t)row * NE;
  float4 v = *(const float4*)(xr + lane * 4);
  float s = v.x + v.y + v.z + v.w;
  #pragma unroll
  for (int o = 32; o; o >>= 1) s += __shfl_xor(s, o);
  float mean = s * (1.f / 256.f);
  float d0 = v.x - mean, d1 = v.y - mean, d2 = v.z - mean, d3 = v.w - mean;
  float q = d0*d0 + d1*d1 + d2*d2 + d3*d3;
  #pragma unroll
  for (int o = 32; o; o >>= 1) q += __shfl_xor(q, o);
  float r = rsqrtf(q * (1.f / 256.f) + 1e-5f);
  int c = lane * 4;
  ushort4 o4;
  o4.x = f2bf(d0 * r * w[c+0] + b[c+0]);
  o4.y = f2bf(d1 * r * w[c+1] + b[c+1]);
  o4.z = f2bf(d2 * r * w[c+2] + b[c+2]);
  o4.w = f2bf(d3 * r * w[c+3] + b[c+3]);
  *(ushort4*)(xn + (size_t)row * NE + c) = o4;
}

// ---------------- K2: uh (f64), top-32 radix select, masked uh -> d_out attn region (f32)
__global__ __launch_bounds__(256) void k_uh(
    const float* __restrict__ u, const float* __restrict__ uw, const float* __restrict__ ub,
    float* __restrict__ uhm) {
  int row = blockIdx.x * 4 + (threadIdx.x >> 6);   // b*256 + p
  int b = row >> 8, p = row & 255;
  int lane = threadIdx.x & 63;
  double uh[NH][4];
  #pragma unroll
  for (int h = 0; h < NH; h++) {
    double bb = (double)ub[h];
    uh[h][0] = bb; uh[h][1] = bb; uh[h][2] = bb; uh[h][3] = bb;
  }
  #pragma unroll
  for (int uu = 0; uu < NU; uu++) {
    float4 uv = *(const float4*)(u + (((size_t)b * NU + uu) * NP + p) * NP + lane * 4);
    #pragma unroll
    for (int h = 0; h < NH; h++) {
      double w = (double)uw[h * NU + uu];
      uh[h][0] += w * (double)uv.x;
      uh[h][1] += w * (double)uv.y;
      uh[h][2] += w * (double)uv.z;
      uh[h][3] += w * (double)uv.w;
    }
  }
  u64 ib[4];
  #pragma unroll
  for (int i = 0; i < 4; i++) {
    double imp = 0.0;
    #pragma unroll
    for (int h = 0; h < NH; h++) imp += fabs(uh[h][i]);
    ib[i] = (u64)__double_as_longlong(imp);   // imp >= 0 -> monotonic bits
  }
  // radix-select the 32nd-largest imp bit pattern across the 256 row values
  u64 res = 0;
  for (int bit = 62; bit >= 0; --bit) {
    u64 cand = res | (1ull << bit);
    int c = __popcll(__ballot(ib[0] >= cand)) + __popcll(__ballot(ib[1] >= cand))
          + __popcll(__ballot(ib[2] >= cand)) + __popcll(__ballot(ib[3] >= cand));
    if (c >= 32) res = cand;
  }
  #pragma unroll
  for (int h = 0; h < NH; h++) {
    float4 o;
    o.x = (ib[0] >= res) ? (float)uh[h][0] : -1e9f;
    o.y = (ib[1] >= res) ? (float)uh[h][1] : -1e9f;
    o.z = (ib[2] >= res) ? (float)uh[h][2] : -1e9f;
    o.w = (ib[3] >= res) ? (float)uh[h][3] : -1e9f;
    *(float4*)(uhm + (((size_t)(b * NH + h)) * NP + p) * NP + lane * 4) = o;
  }
}

// ---------------- generic bf16 MFMA GEMM: C[M][N] = A[M][K] * BT[N][K]^T ----
__device__ __forceinline__ int lswz(int r, int g) {  // XOR swizzle on 16B groups
  return r * 32 + ((g ^ ((r >> 1) & 3)) << 3);
}

template<class Epi>
__global__ __launch_bounds__(256) void k_gemm(
    const u16* __restrict__ A, const u16* __restrict__ BT, int K, Epi epi) {
  __shared__ __align__(16) u16 As[64 * 32];
  __shared__ __align__(16) u16 Bs[64 * 32];
  int m0 = blockIdx.x * 64, n0 = blockIdx.y * 64;
  int t = threadIdx.x;
  int ar = t >> 2, ag = t & 3;
  const u16* Ap = A + (size_t)(m0 + ar) * K + ag * 8;
  const u16* Bp = BT + (size_t)(n0 + ar) * K + ag * 8;
  int lane = t & 63, wv = t >> 6;
  int fr = lane & 15, fg = lane >> 4;
  int wm = (wv >> 1) * 32, wn = (wv & 1) * 32;
  int sidx = lswz(ar, ag);
  int ia0 = lswz(wm + fr, fg),      ia1 = lswz(wm + 16 + fr, fg);
  int ibx0 = lswz(wn + fr, fg),     ibx1 = lswz(wn + 16 + fr, fg);
  f32x4 acc00 = {0.f,0.f,0.f,0.f}, acc01 = {0.f,0.f,0.f,0.f};
  f32x4 acc10 = {0.f,0.f,0.f,0.f}, acc11 = {0.f,0.f,0.f,0.f};
  for (int k0 = 0; k0 < K; k0 += 32) {
    short8 av = *(const short8*)(Ap + k0);
    short8 bv = *(const short8*)(Bp + k0);
    __syncthreads();
    *(short8*)(As + sidx) = av;
    *(short8*)(Bs + sidx) = bv;
    __syncthreads();
    short8 a0 = *(const short8*)(As + ia0);
    short8 a1 = *(const short8*)(As + ia1);
    short8 b0 = *(const short8*)(Bs + ibx0);
    short8 b1 = *(const short8*)(Bs + ibx1);
    acc00 = __builtin_amdgcn_mfma_f32_16x16x32_bf16(a0, b0, acc00, 0, 0, 0);
    acc01 = __builtin_amdgcn_mfma_f32_16x16x32_bf16(a0, b1, acc01, 0, 0, 0);
    acc10 = __builtin_amdgcn_mfma_f32_16x16x32_bf16(a1, b0, acc10, 0, 0, 0);
    acc11 = __builtin_amdgcn_mfma_f32_16x16x32_bf16(a1, b1, acc11, 0, 0, 0);
  }
  #pragma unroll
  for (int jj = 0; jj < 4; jj++) {
    int mr0 = m0 + wm + fg * 4 + jj, mr1 = mr0 + 16;
    int nc0 = n0 + wn + fr,          nc1 = nc0 + 16;
    epi(mr0, nc0, acc00[jj]);
    epi(mr0, nc1, acc01[jj]);
    epi(mr1, nc0, acc10[jj]);
    epi(mr1, nc1, acc11[jj]);
  }
}

struct EpiQKV {
  u16 *q, *k, *vT;
  __device__ __forceinline__ void operator()(int m, int n, float v) const {
    int b = m >> 8, p = m & 255;
    int h = (n >> 5) & 7, d = n & 31;
    u16 bv = f2bf(v);
    if (n < 256)       q [(((size_t)(b*NH + h)) * NP + p) * NHD + d] = bv;
    else if (n < 512)  k [(((size_t)(b*NH + h)) * NP + p) * NHD + d] = bv;
    else               vT[(((size_t)(b*NH + h)) * NHD + d) * NP + p] = bv;
  }
};
struct EpiWo {
  const float* bo; float* ao;
  __device__ __forceinline__ void operator()(int m, int n, float v) const {
    ao[(size_t)m * NE + n] = v + bo[n];
  }
};
struct EpiFFN1 {
  const float* b1; u16* tb;
  __device__ __forceinline__ void operator()(int m, int n, float v) const {
    float s = v + b1[n];
    tb[(size_t)m * NDFF + n] = f2bf(s / (1.f + __expf(-s)));   // silu
  }
};
struct EpiFFN2 {
  const float* b2; const float* hb; float* out0;
  __device__ __forceinline__ void operator()(int m, int n, float v) const {
    out0[(size_t)m * NE + n] = v + b2[n] + hb[(size_t)m * NE + n];
  }
};

// ---------------- K4: fused attention per (b,h, 16-row tile) ---------------
__global__ __launch_bounds__(64) void k_attn(
    const u16* __restrict__ qb, const u16* __restrict__ kb, const u16* __restrict__ vTb,
    float* __restrict__ attn, u16* __restrict__ ctx) {
  int bh = blockIdx.x >> 4;
  int r0 = (blockIdx.x & 15) << 4;
  int lane = threadIdx.x;
  int fr = lane & 15, fg = lane >> 4;
  __shared__ __align__(16) float logits[16 * 256];
  __shared__ __align__(16) u16 ps[16 * 256];

  // load masked uh tile (f32, staged in d_out attn region)
  float* uhp = attn + ((size_t)bh * NP + r0) * NP;
  #pragma unroll
  for (int i = 0; i < 16; i++)
    *(float4*)(logits + i * 256 + lane * 4) = *(const float4*)(uhp + i * 256 + lane * 4);

  const u16* qp = qb + ((size_t)bh * NP + r0) * NHD;
  short8 af = *(const short8*)(qp + fr * NHD + fg * 8);
  const u16* kp = kb + (size_t)bh * NP * NHD;
  __syncthreads();
  const float scale = 0.17677669529663687f;   // 1/sqrt(32)
  #pragma unroll
  for (int nb = 0; nb < 16; nb++) {
    short8 bf = *(const short8*)(kp + (nb * 16 + fr) * NHD + fg * 8);
    f32x4 sc = {0.f,0.f,0.f,0.f};
    sc = __builtin_amdgcn_mfma_f32_16x16x32_bf16(af, bf, sc, 0, 0, 0);
    #pragma unroll
    for (int jj = 0; jj < 4; jj++)
      logits[(fg * 4 + jj) * 256 + nb * 16 + fr] += sc[jj] * scale;
  }
  __syncthreads();
  // wave-wide softmax per row; write attn f32 out; stash bf16 P (swizzled) for ctx MFMA
  for (int r = 0; r < 16; r++) {
    float v0 = logits[r * 256 + lane];
    float v1 = logits[r * 256 + lane + 64];
    float v2 = logits[r * 256 + lane + 128];
    float v3 = logits[r * 256 + lane + 192];
    float mx = fmaxf(fmaxf(v0, v1), fmaxf(v2, v3));
    #pragma unroll
    for (int o = 32; o; o >>= 1) mx = fmaxf(mx, __shfl_xor(mx, o));
    float e0 = __expf(v0 - mx), e1 = __expf(v1 - mx), e2 = __expf(v2 - mx), e3 = __expf(v3 - mx);
    float s = e0 + e1 + e2 + e3;
    #pragma unroll
    for (int o = 32; o; o >>= 1) s += __shfl_xor(s, o);
    float inv = 1.f / s;
    e0 *= inv; e1 *= inv; e2 *= inv; e3 *= inv;
    float* arow = attn + ((size_t)bh * NP + r0 + r) * NP;
    arow[lane] = e0; arow[lane + 64] = e1; arow[lane + 128] = e2; arow[lane + 192] = e3;
    int rs = r & 7;
    int c0 = lane, c1 = lane + 64, c2 = lane + 128, c3 = lane + 192;
    ps[r * 256 + (((c0 >> 3) ^ rs) << 3) + (c0 & 7)] = f2bf(e0);
    ps[r * 256 + (((c1 >> 3) ^ rs) << 3) + (c1 & 7)] = f2bf(e1);
    ps[r * 256 + (((c2 >> 3) ^ rs) << 3) + (c2 & 7)] = f2bf(e2);
    ps[r * 256 + (((c3 >> 3) ^ rs) << 3) + (c3 & 7)] = f2bf(e3);
  }
  __syncthreads();
  // ctx = P @ V  via vT [b][h][d][q]
  const u16* vp = vTb + (size_t)bh * NHD * NP;
  f32x4 c0a = {0.f,0.f,0.f,0.f}, c1a = {0.f,0.f,0.f,0.f};
  #pragma unroll
  for (int kk = 0; kk < 8; kk++) {
    int cc = kk * 32 + fg * 8;
    short8 pa  = *(const short8*)(ps + fr * 256 + (((kk * 4 + fg) ^ (fr & 7)) << 3));
    short8 vb0 = *(const short8*)(vp + fr * NP + cc);
    short8 vb1 = *(const short8*)(vp + (16 + fr) * NP + cc);
    c0a = __builtin_amdgcn_mfma_f32_16x16x32_bf16(pa, vb0, c0a, 0, 0, 0);
    c1a = __builtin_amdgcn_mfma_f32_16x16x32_bf16(pa, vb1, c1a, 0, 0, 0);
  }
  int b = bh >> 3, h = bh & 7;
  #pragma unroll
  for (int jj = 0; jj < 4; jj++) {
    int prow = r0 + fg * 4 + jj;
    u16* crow = ctx + ((size_t)(b * NP + prow)) * NE + h * NHD;
    crow[fr]      = f2bf(c0a[jj]);
    crow[16 + fr] = f2bf(c1a[jj]);
  }
}

// ---------------- K6: LN2 + residual + RMSNorm ------------------------------
__global__ __launch_bounds__(256) void k_ln2rms(
    const float* __restrict__ ao, const float* __restrict__ x,
    const float* __restrict__ w, const float* __restrict__ b, const float* __restrict__ rw,
    float* __restrict__ hbuf, u16* __restrict__ hn) {
  int row = blockIdx.x * 4 + (threadIdx.x >> 6);
  int lane = threadIdx.x & 63;
  float4 v = *(const float4*)(ao + (size_t)row * NE + lane * 4);
  float s = v.x + v.y + v.z + v.w;
  #pragma unroll
  for (int o = 32; o; o >>= 1) s += __shfl_xor(s, o);
  float mean = s * (1.f / 256.f);
  float d0 = v.x - mean, d1 = v.y - mean, d2 = v.z - mean, d3 = v.w - mean;
  float q = d0*d0 + d1*d1 + d2*d2 + d3*d3;
  #pragma unroll
  for (int o = 32; o; o >>= 1) q += __shfl_xor(q, o);
  float r = rsqrtf(q * (1.f / 256.f) + 1e-5f);
  float4 xv = *(const float4*)(x + (size_t)row * NE + lane * 4);
  int c = lane * 4;
  float h0 = d0 * r * w[c+0] + b[c+0] + xv.x;
  float h1 = d1 * r * w[c+1] + b[c+1] + xv.y;
  float h2 = d2 * r * w[c+2] + b[c+2] + xv.z;
  float h3 = d3 * r * w[c+3] + b[c+3] + xv.w;
  *(float4*)(hbuf + (size_t)row * NE + c) = make_float4(h0, h1, h2, h3);
  float ss = h0*h0 + h1*h1 + h2*h2 + h3*h3;
  #pragma unroll
  for (int o = 32; o; o >>= 1) ss += __shfl_xor(ss, o);
  float rm = rsqrtf(ss * (1.f / 256.f) + 1.1920929e-07f);
  ushort4 o4;
  o4.x = f2bf(h0 * rm * rw[c+0]);
  o4.y = f2bf(h1 * rm * rw[c+1]);
  o4.z = f2bf(h2 * rm * rw[c+2]);
  o4.w = f2bf(h3 * rm * rw[c+3]);
  *(ushort4*)(hn + (size_t)row * NE + c) = o4;
}

// ---------------- launch ----------------------------------------------------
extern "C" void kernel_launch(void* const* d_in, const int* in_sizes, int n_in,
                              void* d_out, int out_size, void* d_ws, size_t ws_size,
                              hipStream_t stream) {
  (void)in_sizes; (void)n_in; (void)out_size; (void)ws_size;
  const float* x    = (const float*)d_in[0];
  const float* u    = (const float*)d_in[1];
  const float* n1w  = (const float*)d_in[2];
  const float* n1b  = (const float*)d_in[3];
  const float* wq   = (const float*)d_in[4];
  const float* wk   = (const float*)d_in[5];
  const float* wv   = (const float*)d_in[6];
  const float* wo   = (const float*)d_in[7];
  const float* bo   = (const float*)d_in[8];
  const float* uw   = (const float*)d_in[9];
  const float* ub   = (const float*)d_in[10];
  const float* n2w  = (const float*)d_in[11];
  const float* n2b  = (const float*)d_in[12];
  const float* rmsw = (const float*)d_in[13];
  const float* w1   = (const float*)d_in[14];
  const float* b1   = (const float*)d_in[15];
  const float* w2   = (const float*)d_in[16];
  const float* b2   = (const float*)d_in[17];
  float* out0 = (float*)d_out;
  float* attn = out0 + (size_t)NM * NE;   // second tuple output; doubles as uh scratch
  char* ws = (char*)d_ws;                 // needs ~86 MB
  u16* wqkvT = (u16*)(ws + 0x000000);
  u16* woT   = (u16*)(ws + 0x060000);
  u16* w1T   = (u16*)(ws + 0x080000);
  u16* w2T   = (u16*)(ws + 0x100000);
  u16* qb    = (u16*)(ws + 0x200000);
  u16* kb    = (u16*)(ws + 0xA00000);
  u16* vTb   = (u16*)(ws + 0x1200000);
  u16* xn    = (u16*)(ws + 0x1A00000);
  u16* ctx   = (u16*)(ws + 0x2200000);
  float* ao  = (float*)(ws + 0x2A00000);
  float* hb  = (float*)(ws + 0x3A00000);
  u16* hn    = (u16*)(ws + 0x4A00000);
  u16* tb    = (u16*)(ws + 0x200000);     // overlaps q/k/vT/xn (dead before FFN1)

  k_prep<<<dim3(256), dim3(256), 0, stream>>>(wq, wk, wv, wo, w1, w2, wqkvT, woT, w1T, w2T);
  k_ln1<<<dim3(NM/4), dim3(256), 0, stream>>>(x, n1w, n1b, xn);
  k_uh<<<dim3(NM/4), dim3(256), 0, stream>>>(u, uw, ub, attn);
  k_gemm<<<dim3(NM/64, 768/64), dim3(256), 0, stream>>>(xn, wqkvT, NE, EpiQKV{qb, kb, vTb});
  k_attn<<<dim3(NB*NH*16), dim3(64), 0, stream>>>(qb, kb, vTb, attn, ctx);
  k_gemm<<<dim3(NM/64, NE/64), dim3(256), 0, stream>>>(ctx, woT, NE, EpiWo{bo, ao});
  k_ln2rms<<<dim3(NM/4), dim3(256), 0, stream>>>(ao, x, n2w, n2b, rmsw, hb, hn);
  k_gemm<<<dim3(NM/64, NDFF/64), dim3(256), 0, stream>>>(hn, w1T, NE, EpiFFN1{b1, tb});
  k_gemm<<<dim3(NM/64, NE/64), dim3(256), 0, stream>>>(tb, w2T, NDFF, EpiFFN2{b2, hb, out0});
}

// Round 2
// 480.665 us; speedup vs baseline: 1.0137x; 1.0137x over previous
//
#include <hip/hip_runtime.h>
#include <hip/hip_bf16.h>

typedef unsigned short u16;
typedef unsigned long long u64;
typedef __attribute__((ext_vector_type(8))) short short8;
typedef __attribute__((ext_vector_type(4))) float f32x4;

#define NB 64
#define NP 256
#define NE 256
#define NH 8
#define NHD 32
#define NU 6
#define NDFF 1024
#define NM (NB*NP)   // 16384 tokens

__device__ __forceinline__ u16 f2bf(float f) {
  unsigned u = __float_as_uint(f);
  unsigned r = 0x7fffu + ((u >> 16) & 1u);
  return (u16)((u + r) >> 16);
}
__device__ __forceinline__ float bf2f(u16 v) {
  unsigned u = ((unsigned)v) << 16;
  return __uint_as_float(u);
}

// async global->LDS, 16B per lane, dest = wave-uniform base + lane*16
__device__ __forceinline__ void gl_lds16(const u16* g, u16* l) {
  __builtin_amdgcn_global_load_lds(
      (const __attribute__((address_space(1))) unsigned int*)g,
      (__attribute__((address_space(3))) unsigned int*)l, 16, 0, 0);
}

// ---------------- K0: transpose weights to bf16 (B^T layouts for MFMA) ----
__global__ __launch_bounds__(256) void k_prep(
    const float* __restrict__ wq, const float* __restrict__ wk, const float* __restrict__ wv,
    const float* __restrict__ wo, const float* __restrict__ w1, const float* __restrict__ w2,
    u16* __restrict__ wqkvT, u16* __restrict__ woT, u16* __restrict__ w1T, u16* __restrict__ w2T) {
  int tid = blockIdx.x * 256 + threadIdx.x;
  int stride = gridDim.x * 256;
  for (int i = tid; i < 768 * 256; i += stride) {
    int n = i >> 8, kk = i & 255;
    const float* s = (n < 256) ? wq : ((n < 512) ? wk : wv);
    wqkvT[i] = f2bf(s[kk * 256 + (n & 255)]);
  }
  for (int i = tid; i < 256 * 256; i += stride)  { int n = i >> 8,  kk = i & 255;  woT[i] = f2bf(wo[kk * 256 + n]); }
  for (int i = tid; i < 1024 * 256; i += stride) { int n = i >> 8,  kk = i & 255;  w1T[i] = f2bf(w1[kk * 1024 + n]); }
  for (int i = tid; i < 256 * 1024; i += stride) { int n = i >> 10, kk = i & 1023; w2T[i] = f2bf(w2[kk * 256 + n]); }
}

// ---------------- K1: LayerNorm1 -> xn bf16 [16384][256] --------------------
__global__ __launch_bounds__(256) void k_ln1(
    const float* __restrict__ x, const float* __restrict__ w, const float* __restrict__ b,
    u16* __restrict__ xn) {
  int row = blockIdx.x * 4 + (threadIdx.x >> 6);
  int lane = threadIdx.x & 63;
  const float* xr = x + (size_t)row * NE;
  float4 v = *(const float4*)(xr + lane * 4);
  float s = v.x + v.y + v.z + v.w;
  #pragma unroll
  for (int o = 32; o; o >>= 1) s += __shfl_xor(s, o);
  float mean = s * (1.f / 256.f);
  float d0 = v.x - mean, d1 = v.y - mean, d2 = v.z - mean, d3 = v.w - mean;
  float q = d0*d0 + d1*d1 + d2*d2 + d3*d3;
  #pragma unroll
  for (int o = 32; o; o >>= 1) q += __shfl_xor(q, o);
  float r = rsqrtf(q * (1.f / 256.f) + 1e-5f);
  int c = lane * 4;
  ushort4 o4;
  o4.x = f2bf(d0 * r * w[c+0] + b[c+0]);
  o4.y = f2bf(d1 * r * w[c+1] + b[c+1]);
  o4.z = f2bf(d2 * r * w[c+2] + b[c+2]);
  o4.w = f2bf(d3 * r * w[c+3] + b[c+3]);
  *(ushort4*)(xn + (size_t)row * NE + c) = o4;
}

// ---------------- K_GEMM: 128x128 tile, BK=32, global_load_lds staging ------
// C[M][N] = A[M][K] * BT[N][K]^T, epilogue via functor
template<class Epi>
__global__ __launch_bounds__(256, 4) void k_gemm128(
    const u16* __restrict__ A, const u16* __restrict__ BT, int K, Epi epi) {
  __shared__ __align__(16) u16 As[128 * 32];
  __shared__ __align__(16) u16 Bs[128 * 32];
  const int t = threadIdx.x;
  const int m0 = blockIdx.x * 128, n0 = blockIdx.y * 128;
  const int lane = t & 63, wv = t >> 6;
  const int fr = lane & 15, fg = lane >> 4;
  const int wm = (wv >> 1) * 64, wn = (wv & 1) * 64;
  const u16* Ap = A + (size_t)(m0 + (t >> 2)) * K + (t & 3) * 8;
  const u16* Bp = BT + (size_t)(n0 + (t >> 2)) * K + (t & 3) * 8;
  u16* lA = As + wv * 512;                 // 1024 B per wave
  u16* lB = Bs + wv * 512;
  f32x4 acc[4][4] = {};
  for (int k0 = 0; k0 < K; k0 += 32) {
    __syncthreads();                        // prev tile reads done
    gl_lds16(Ap + k0, lA);
    gl_lds16(Ap + k0 + (size_t)64 * K, lA + 2048);
    gl_lds16(Bp + k0, lB);
    gl_lds16(Bp + k0 + (size_t)64 * K, lB + 2048);
    __syncthreads();                        // staged data visible (vmcnt drain)
    short8 a[4], b[4];
    #pragma unroll
    for (int i = 0; i < 4; i++) a[i] = *(const short8*)(As + (wm + i * 16 + fr) * 32 + fg * 8);
    #pragma unroll
    for (int j = 0; j < 4; j++) b[j] = *(const short8*)(Bs + (wn + j * 16 + fr) * 32 + fg * 8);
    #pragma unroll
    for (int i = 0; i < 4; i++)
      #pragma unroll
      for (int j = 0; j < 4; j++)
        acc[i][j] = __builtin_amdgcn_mfma_f32_16x16x32_bf16(a[i], b[j], acc[i][j], 0, 0, 0);
  }
  #pragma unroll
  for (int i = 0; i < 4; i++)
    #pragma unroll
    for (int j = 0; j < 4; j++)
      #pragma unroll
      for (int jj = 0; jj < 4; jj++)
        epi(m0 + wm + i * 16 + fg * 4 + jj, n0 + wn + j * 16 + fr, acc[i][j][jj]);
}

struct EpiQKV {
  u16 *q, *k, *vT;
  __device__ __forceinline__ void operator()(int m, int n, float v) const {
    int b = m >> 8, p = m & 255;
    int h = (n >> 5) & 7, d = n & 31;
    u16 bv = f2bf(v);
    if (n < 256)       q [(((size_t)(b*NH + h)) * NP + p) * NHD + d] = bv;
    else if (n < 512)  k [(((size_t)(b*NH + h)) * NP + p) * NHD + d] = bv;
    else               vT[(((size_t)(b*NH + h)) * NHD + d) * NP + p] = bv;
  }
};
struct EpiWo {
  const float* bo; float* ao;
  __device__ __forceinline__ void operator()(int m, int n, float v) const {
    ao[(size_t)m * NE + n] = v + bo[n];
  }
};
struct EpiFFN1 {
  const float* b1; u16* tb;
  __device__ __forceinline__ void operator()(int m, int n, float v) const {
    float s = v + b1[n];
    tb[(size_t)m * NDFF + n] = f2bf(s / (1.f + __expf(-s)));   // silu
  }
};
struct EpiFFN2 {
  const float* b2; const float* hb; float* out0;
  __device__ __forceinline__ void operator()(int m, int n, float v) const {
    out0[(size_t)m * NE + n] = v + b2[n] + hb[(size_t)m * NE + n];
  }
};

// ---------------- K_FATTN: fused uh + top-32 + attention --------------------
// grid = (B * 16); block = 512 (8 waves). Block handles (b, rows r0..r0+15)
// for ALL heads. Phase 1: wave w computes uh (f64) for rows r0+2w, r0+2w+1,
// radix-selects top-32, writes masked bf16 bias into LDS [h][16][256].
// Phase 2: wave w = head w; QK^T -> +bias -> softmax -> attn out; P staged in
// own LDS slice (XOR-swizzled) -> PV -> ctx.
__global__ __launch_bounds__(512, 4) void k_fattn(
    const float* __restrict__ u, const float* __restrict__ uw, const float* __restrict__ ub,
    const u16* __restrict__ qb, const u16* __restrict__ kb, const u16* __restrict__ vTb,
    float* __restrict__ attn, u16* __restrict__ ctx) {
  __shared__ __align__(16) u16 bias[NH * 16 * 256];   // 64 KB; per-head slice reused for P
  const int b = blockIdx.x >> 4;
  const int r0 = (blockIdx.x & 15) << 4;
  const int w = threadIdx.x >> 6;
  const int lane = threadIdx.x & 63;
  const int fr = lane & 15, fg = lane >> 4;
  const u16 NEGBF = f2bf(-1e9f);

  // ---- phase 1: uh (f64) + top-32 per row
  for (int rr = 0; rr < 2; rr++) {
    const int p = r0 + 2 * w + rr;
    const float* up = u + ((size_t)b * NU * NP + p) * NP + lane * 4;
    double uh[NH][4];
    #pragma unroll
    for (int h = 0; h < NH; h++) {
      double bb = (double)ub[h];
      uh[h][0] = bb; uh[h][1] = bb; uh[h][2] = bb; uh[h][3] = bb;
    }
    #pragma unroll
    for (int uu = 0; uu < NU; uu++) {
      float4 uv = *(const float4*)(up + (size_t)uu * (NP * NP));
      #pragma unroll
      for (int h = 0; h < NH; h++) {
        double ww = (double)uw[h * NU + uu];
        uh[h][0] += ww * (double)uv.x;
        uh[h][1] += ww * (double)uv.y;
        uh[h][2] += ww * (double)uv.z;
        uh[h][3] += ww * (double)uv.w;
      }
    }
    u64 ib[4];
    #pragma unroll
    for (int i = 0; i < 4; i++) {
      double imp = 0.0;
      #pragma unroll
      for (int h = 0; h < NH; h++) imp += fabs(uh[h][i]);
      ib[i] = (u64)__double_as_longlong(imp);
    }
    u64 res = 0;
    for (int bit = 62; bit >= 0; --bit) {
      u64 cand = res | (1ull << bit);
      int c = __popcll(__ballot(ib[0] >= cand)) + __popcll(__ballot(ib[1] >= cand))
            + __popcll(__ballot(ib[2] >= cand)) + __popcll(__ballot(ib[3] >= cand));
      if (c >= 32) res = cand;
    }
    const int rl = 2 * w + rr;
    #pragma unroll
    for (int h = 0; h < NH; h++) {
      ushort4 o;
      o.x = (ib[0] >= res) ? f2bf((float)uh[h][0]) : NEGBF;
      o.y = (ib[1] >= res) ? f2bf((float)uh[h][1]) : NEGBF;
      o.z = (ib[2] >= res) ? f2bf((float)uh[h][2]) : NEGBF;
      o.w = (ib[3] >= res) ? f2bf((float)uh[h][3]) : NEGBF;
      *(ushort4*)(bias + (h * 16 + rl) * 256 + lane * 4) = o;
    }
  }
  __syncthreads();

  // ---- phase 2: attention, wave w = head w over rows r0..r0+15
  const size_t bh = (size_t)b * NH + w;
  const u16* qp = qb + (bh * NP + r0) * NHD;
  short8 af = *(const short8*)(qp + fr * NHD + fg * 8);
  const u16* kp = kb + bh * NP * NHD;
  const float scale = 0.17677669529663687f;   // 1/sqrt(32)
  f32x4 sc[16];
  #pragma unroll
  for (int nb = 0; nb < 16; nb++) {
    short8 bfr = *(const short8*)(kp + (nb * 16 + fr) * NHD + fg * 8);
    f32x4 z = {0.f, 0.f, 0.f, 0.f};
    z = __builtin_amdgcn_mfma_f32_16x16x32_bf16(af, bfr, z, 0, 0, 0);
    #pragma unroll
    for (int jj = 0; jj < 4; jj++)
      sc[nb][jj] = z[jj] * scale + bf2f(bias[(w * 16 + fg * 4 + jj) * 256 + nb * 16 + fr]);
  }
  // softmax per row (row = fg*4+jj); reduce over nb in-register, over fr via shfl
  float mx[4] = {-1e30f, -1e30f, -1e30f, -1e30f};
  #pragma unroll
  for (int nb = 0; nb < 16; nb++)
    #pragma unroll
    for (int jj = 0; jj < 4; jj++) mx[jj] = fmaxf(mx[jj], sc[nb][jj]);
  #pragma unroll
  for (int o = 1; o < 16; o <<= 1)
    #pragma unroll
    for (int jj = 0; jj < 4; jj++) mx[jj] = fmaxf(mx[jj], __shfl_xor(mx[jj], o));
  float sum[4] = {0.f, 0.f, 0.f, 0.f};
  #pragma unroll
  for (int nb = 0; nb < 16; nb++)
    #pragma unroll
    for (int jj = 0; jj < 4; jj++) {
      sc[nb][jj] = __expf(sc[nb][jj] - mx[jj]);
      sum[jj] += sc[nb][jj];
    }
  #pragma unroll
  for (int o = 1; o < 16; o <<= 1)
    #pragma unroll
    for (int jj = 0; jj < 4; jj++) sum[jj] += __shfl_xor(sum[jj], o);
  float inv[4];
  #pragma unroll
  for (int jj = 0; jj < 4; jj++) inv[jj] = 1.f / sum[jj];

  float* ap = attn + (bh * NP + r0 + fg * 4) * NP;
  u16* ps = bias + w * 4096;                 // own slice, reuse as P buffer
  #pragma unroll
  for (int nb = 0; nb < 16; nb++)
    #pragma unroll
    for (int jj = 0; jj < 4; jj++) {
      float e = sc[nb][jj] * inv[jj];
      ap[jj * 256 + nb * 16 + fr] = e;
      int row = fg * 4 + jj, col = nb * 16 + fr;
      ps[row * 256 + ((((col >> 3) ^ (row & 7)) << 3) | (col & 7))] = f2bf(e);
    }

  // PV: ctx[16][32] = P[16][256] @ V[256][32] via vT [d][p]
  const u16* vp = vTb + bh * NHD * NP;
  f32x4 c0 = {0.f, 0.f, 0.f, 0.f}, c1 = {0.f, 0.f, 0.f, 0.f};
  #pragma unroll
  for (int kk = 0; kk < 8; kk++) {
    short8 pa = *(const short8*)(ps + fr * 256 + (((kk * 4 + fg) ^ (fr & 7)) << 3));
    short8 v0 = *(const short8*)(vp + fr * NP + kk * 32 + fg * 8);
    short8 v1 = *(const short8*)(vp + (16 + fr) * NP + kk * 32 + fg * 8);
    c0 = __builtin_amdgcn_mfma_f32_16x16x32_bf16(pa, v0, c0, 0, 0, 0);
    c1 = __builtin_amdgcn_mfma_f32_16x16x32_bf16(pa, v1, c1, 0, 0, 0);
  }
  #pragma unroll
  for (int jj = 0; jj < 4; jj++) {
    int prow = r0 + fg * 4 + jj;
    u16* crow = ctx + ((size_t)(b * NP + prow)) * NE + w * NHD;
    crow[fr]      = f2bf(c0[jj]);
    crow[16 + fr] = f2bf(c1[jj]);
  }
}

// ---------------- K6: LN2 + residual + RMSNorm ------------------------------
__global__ __launch_bounds__(256) void k_ln2rms(
    const float* __restrict__ ao, const float* __restrict__ x,
    const float* __restrict__ w, const float* __restrict__ b, const float* __restrict__ rw,
    float* __restrict__ hbuf, u16* __restrict__ hn) {
  int row = blockIdx.x * 4 + (threadIdx.x >> 6);
  int lane = threadIdx.x & 63;
  float4 v = *(const float4*)(ao + (size_t)row * NE + lane * 4);
  float s = v.x + v.y + v.z + v.w;
  #pragma unroll
  for (int o = 32; o; o >>= 1) s += __shfl_xor(s, o);
  float mean = s * (1.f / 256.f);
  float d0 = v.x - mean, d1 = v.y - mean, d2 = v.z - mean, d3 = v.w - mean;
  float q = d0*d0 + d1*d1 + d2*d2 + d3*d3;
  #pragma unroll
  for (int o = 32; o; o >>= 1) q += __shfl_xor(q, o);
  float r = rsqrtf(q * (1.f / 256.f) + 1e-5f);
  float4 xv = *(const float4*)(x + (size_t)row * NE + lane * 4);
  int c = lane * 4;
  float h0 = d0 * r * w[c+0] + b[c+0] + xv.x;
  float h1 = d1 * r * w[c+1] + b[c+1] + xv.y;
  float h2 = d2 * r * w[c+2] + b[c+2] + xv.z;
  float h3 = d3 * r * w[c+3] + b[c+3] + xv.w;
  *(float4*)(hbuf + (size_t)row * NE + c) = make_float4(h0, h1, h2, h3);
  float ss = h0*h0 + h1*h1 + h2*h2 + h3*h3;
  #pragma unroll
  for (int o = 32; o; o >>= 1) ss += __shfl_xor(ss, o);
  float rm = rsqrtf(ss * (1.f / 256.f) + 1.1920929e-07f);
  ushort4 o4;
  o4.x = f2bf(h0 * rm * rw[c+0]);
  o4.y = f2bf(h1 * rm * rw[c+1]);
  o4.z = f2bf(h2 * rm * rw[c+2]);
  o4.w = f2bf(h3 * rm * rw[c+3]);
  *(ushort4*)(hn + (size_t)row * NE + c) = o4;
}

// ---------------- launch ----------------------------------------------------
extern "C" void kernel_launch(void* const* d_in, const int* in_sizes, int n_in,
                              void* d_out, int out_size, void* d_ws, size_t ws_size,
                              hipStream_t stream) {
  (void)in_sizes; (void)n_in; (void)out_size; (void)ws_size;
  const float* x    = (const float*)d_in[0];
  const float* u    = (const float*)d_in[1];
  const float* n1w  = (const float*)d_in[2];
  const float* n1b  = (const float*)d_in[3];
  const float* wq   = (const float*)d_in[4];
  const float* wk   = (const float*)d_in[5];
  const float* wv   = (const float*)d_in[6];
  const float* wo   = (const float*)d_in[7];
  const float* bo   = (const float*)d_in[8];
  const float* uw   = (const float*)d_in[9];
  const float* ub   = (const float*)d_in[10];
  const float* n2w  = (const float*)d_in[11];
  const float* n2b  = (const float*)d_in[12];
  const float* rmsw = (const float*)d_in[13];
  const float* w1   = (const float*)d_in[14];
  const float* b1   = (const float*)d_in[15];
  const float* w2   = (const float*)d_in[16];
  const float* b2   = (const float*)d_in[17];
  float* out0 = (float*)d_out;
  float* attn = out0 + (size_t)NM * NE;   // second tuple output
  char* ws = (char*)d_ws;                 // needs ~86 MB
  u16* wqkvT = (u16*)(ws + 0x000000);
  u16* woT   = (u16*)(ws + 0x060000);
  u16* w1T   = (u16*)(ws + 0x080000);
  u16* w2T   = (u16*)(ws + 0x100000);
  u16* qb    = (u16*)(ws + 0x200000);
  u16* kb    = (u16*)(ws + 0xA00000);
  u16* vTb   = (u16*)(ws + 0x1200000);
  u16* xn    = (u16*)(ws + 0x1A00000);
  u16* ctx   = (u16*)(ws + 0x2200000);
  float* ao  = (float*)(ws + 0x2A00000);
  float* hb  = (float*)(ws + 0x3A00000);
  u16* hn    = (u16*)(ws + 0x4A00000);
  u16* tb    = (u16*)(ws + 0x200000);     // overlaps q/k/vT/xn (dead before FFN1)

  k_prep<<<dim3(256), dim3(256), 0, stream>>>(wq, wk, wv, wo, w1, w2, wqkvT, woT, w1T, w2T);
  k_ln1<<<dim3(NM/4), dim3(256), 0, stream>>>(x, n1w, n1b, xn);
  k_gemm128<<<dim3(NM/128, 768/128), dim3(256), 0, stream>>>(xn, wqkvT, NE, EpiQKV{qb, kb, vTb});
  k_fattn<<<dim3(NB*16), dim3(512), 0, stream>>>(u, uw, ub, qb, kb, vTb, attn, ctx);
  k_gemm128<<<dim3(NM/128, NE/128), dim3(256), 0, stream>>>(ctx, woT, NE, EpiWo{bo, ao});
  k_ln2rms<<<dim3(NM/4), dim3(256), 0, stream>>>(ao, x, n2w, n2b, rmsw, hb, hn);
  k_gemm128<<<dim3(NM/128, NDFF/128), dim3(256), 0, stream>>>(hn, w1T, NE, EpiFFN1{b1, tb});
  k_gemm128<<<dim3(NM/128, NE/128), dim3(256), 0, stream>>>(tb, w2T, NDFF, EpiFFN2{b2, hb, out0});
}

// Round 6
// 422.974 us; speedup vs baseline: 1.1520x; 1.1364x over previous
//
#include <hip/hip_runtime.h>
#include <hip/hip_bf16.h>

typedef unsigned short u16;
typedef unsigned long long u64;
typedef __attribute__((ext_vector_type(8))) short short8;
typedef __attribute__((ext_vector_type(4))) short s16x4;
typedef __attribute__((ext_vector_type(4))) float f32x4;

#define NB 64
#define NP 256
#define NE 256
#define NH 8
#define NHD 32
#define NU 6
#define NDFF 1024
#define NM (NB*NP)   // 16384 tokens

__device__ __forceinline__ u16 f2bf(float f) {
  unsigned u = __float_as_uint(f);
  unsigned r = 0x7fffu + ((u >> 16) & 1u);
  return (u16)((u + r) >> 16);
}
__device__ __forceinline__ float bf2f(u16 v) {
  return __uint_as_float(((unsigned)v) << 16);
}

// async global->LDS, 16B per lane, dest = wave-uniform base + lane*16
__device__ __forceinline__ void gl_lds16(const u16* g, u16* l) {
  __builtin_amdgcn_global_load_lds(
      (const __attribute__((address_space(1))) unsigned int*)g,
      (__attribute__((address_space(3))) unsigned int*)l, 16, 0, 0);
}

// ---------------- K0: tiled transpose f32 -> bf16^T ------------------------
// segments: 0-191 wq/wk/wv -> wqkvT, 192-255 wo, 256-511 w1, 512-767 w2
__global__ __launch_bounds__(256) void k_prep(
    const float* __restrict__ wq, const float* __restrict__ wk, const float* __restrict__ wv,
    const float* __restrict__ wo, const float* __restrict__ w1, const float* __restrict__ w2,
    u16* __restrict__ wqkvT, u16* __restrict__ woT, u16* __restrict__ w1T, u16* __restrict__ w2T) {
  __shared__ float tile[32][33];
  int bid = blockIdx.x;
  const float* src; u16* dst; int R, C, tr, tc;
  if (bid < 192)      { int m = bid >> 6, t = bid & 63; src = m==0?wq:(m==1?wk:wv); dst = wqkvT + m*256*256; R=256; C=256;  tr=t>>3; tc=t&7;  }
  else if (bid < 256) { int t = bid-192; src=wo; dst=woT; R=256;  C=256;  tr=t>>3; tc=t&7;  }
  else if (bid < 512) { int t = bid-256; src=w1; dst=w1T; R=256;  C=1024; tr=t>>5; tc=t&31; }
  else                { int t = bid-512; src=w2; dst=w2T; R=1024; C=256;  tr=t>>3; tc=t&7;  }
  int r0 = tr*32, c0 = tc*32;
  int rr = threadIdx.x >> 5, cc = threadIdx.x & 31;
  #pragma unroll
  for (int p = 0; p < 4; p++)
    tile[rr + p*8][cc] = src[(size_t)(r0 + rr + p*8) * C + c0 + cc];
  __syncthreads();
  #pragma unroll
  for (int p = 0; p < 4; p++)
    dst[(size_t)(c0 + rr + p*8) * R + r0 + cc] = f2bf(tile[cc][rr + p*8]);
}

// ---------------- K1: LayerNorm1 -> xn bf16 [16384][256] --------------------
__global__ __launch_bounds__(256) void k_ln1(
    const float* __restrict__ x, const float* __restrict__ w, const float* __restrict__ b,
    u16* __restrict__ xn) {
  int row = blockIdx.x * 4 + (threadIdx.x >> 6);
  int lane = threadIdx.x & 63;
  float4 v = *(const float4*)(x + (size_t)row * NE + lane * 4);
  float s = v.x + v.y + v.z + v.w;
  #pragma unroll
  for (int o = 32; o; o >>= 1) s += __shfl_xor(s, o);
  float mean = s * (1.f / 256.f);
  float d0 = v.x - mean, d1 = v.y - mean, d2 = v.z - mean, d3 = v.w - mean;
  float q = d0*d0 + d1*d1 + d2*d2 + d3*d3;
  #pragma unroll
  for (int o = 32; o; o >>= 1) q += __shfl_xor(q, o);
  float r = rsqrtf(q * (1.f / 256.f) + 1e-5f);
  int c = lane * 4;
  ushort4 o4;
  o4.x = f2bf(d0 * r * w[c+0] + b[c+0]);
  o4.y = f2bf(d1 * r * w[c+1] + b[c+1]);
  o4.z = f2bf(d2 * r * w[c+2] + b[c+2]);
  o4.w = f2bf(d3 * r * w[c+3] + b[c+3]);
  *(ushort4*)(xn + (size_t)row * NE + c) = o4;
}

// ---------------- K_GEMM: 128x128 tile, BK=32, gl_lds + swizzled reads ------
template<class Epi>
__global__ __launch_bounds__(256, 4) void k_gemm128(
    const u16* __restrict__ A, const u16* __restrict__ BT, int K, Epi epi) {
  __shared__ __align__(16) u16 As[128 * 32];
  __shared__ __align__(16) u16 Bs[128 * 32];
  const int t = threadIdx.x;
  const int m0 = blockIdx.x * 128, n0 = blockIdx.y * 128;
  const int lane = t & 63, wv = t >> 6;
  const int fr = lane & 15, fg = lane >> 4;
  const int wm = (wv >> 1) * 64, wn = (wv & 1) * 64;
  const int row = t >> 2;
  const int gs = (t & 3) ^ ((row >> 1) & 3);          // pre-swizzled source group
  const u16* Ap = A + (size_t)(m0 + row) * K + gs * 8;
  const u16* Bp = BT + (size_t)(n0 + row) * K + gs * 8;
  u16* lA = As + wv * 512;
  u16* lB = Bs + wv * 512;
  f32x4 acc[4][4] = {};
  for (int k0 = 0; k0 < K; k0 += 32) {
    __syncthreads();
    gl_lds16(Ap + k0, lA);
    gl_lds16(Ap + k0 + (size_t)64 * K, lA + 2048);
    gl_lds16(Bp + k0, lB);
    gl_lds16(Bp + k0 + (size_t)64 * K, lB + 2048);
    __syncthreads();
    short8 a[4], b[4];
    #pragma unroll
    for (int i = 0; i < 4; i++) {
      int ra = wm + i * 16 + fr;
      a[i] = *(const short8*)(As + ra * 32 + ((fg ^ ((ra >> 1) & 3)) << 3));
    }
    #pragma unroll
    for (int j = 0; j < 4; j++) {
      int rb = wn + j * 16 + fr;
      b[j] = *(const short8*)(Bs + rb * 32 + ((fg ^ ((rb >> 1) & 3)) << 3));
    }
    #pragma unroll
    for (int i = 0; i < 4; i++)
      #pragma unroll
      for (int j = 0; j < 4; j++)
        acc[i][j] = __builtin_amdgcn_mfma_f32_16x16x32_bf16(a[i], b[j], acc[i][j], 0, 0, 0);
  }
  #pragma unroll
  for (int i = 0; i < 4; i++)
    #pragma unroll
    for (int j = 0; j < 4; j++)
      #pragma unroll
      for (int jj = 0; jj < 4; jj++)
        epi(m0 + wm + i * 16 + fg * 4 + jj, n0 + wn + j * 16 + fr, acc[i][j][jj]);
}

struct EpiQKV {
  u16 *q, *k, *vT;
  __device__ __forceinline__ void operator()(int m, int n, float v) const {
    int b = m >> 8, p = m & 255;
    int h = (n >> 5) & 7, d = n & 31;
    u16 bv = f2bf(v);
    if (n < 256)       q [(((size_t)(b*NH + h)) * NP + p) * NHD + d] = bv;
    else if (n < 512)  k [(((size_t)(b*NH + h)) * NP + p) * NHD + d] = bv;
    else               vT[(((size_t)(b*NH + h)) * NHD + d) * NP + p] = bv;
  }
};
struct EpiWo {
  const float* bo; float* ao;
  __device__ __forceinline__ void operator()(int m, int n, float v) const {
    ao[(size_t)m * NE + n] = v + bo[n];
  }
};
struct EpiFFN1 {
  const float* b1; u16* tb;
  __device__ __forceinline__ void operator()(int m, int n, float v) const {
    float s = v + b1[n];
    tb[(size_t)m * NDFF + n] = f2bf(s / (1.f + __expf(-s)));   // silu
  }
};
struct EpiFFN2 {
  const float* b2; const float* hb; float* out0;
  __device__ __forceinline__ void operator()(int m, int n, float v) const {
    out0[(size_t)m * NE + n] = v + b2[n] + hb[(size_t)m * NE + n];
  }
};

// ---------------- K_FATTN: fused uh + top-32 + attention --------------------
// grid 1024 XCD-swizzled; block 512 (8 waves). Phase 1: wave w computes f64 uh
// for rows 2w,2w+1 (h-outer, low regs), stashes unmasked bf16 bias in LDS,
// radix-selects top-32, masks in place. Phase 2: wave w = head w; 2-pass QK^T
// (max, then exp in place of bias), coalesced attn f32 rows, in-reg reswizzle,
// PV with inv folded into ctx.
__global__ __launch_bounds__(512, 2) void k_fattn(
    const float* __restrict__ u, const float* __restrict__ uw, const float* __restrict__ ub,
    const u16* __restrict__ qb, const u16* __restrict__ kb, const u16* __restrict__ vTb,
    float* __restrict__ attn, u16* __restrict__ ctx) {
  __shared__ __align__(16) u16 bias[NH * 16 * 256];   // 64 KB
  const int i0 = blockIdx.x;
  const int b = (i0 & 7) * 8 + ((i0 >> 3) & 7);       // all 16 tiles of b on one XCD
  const int r0 = (i0 >> 6) << 4;
  const int w = threadIdx.x >> 6;
  const int lane = threadIdx.x & 63;
  const int fr = lane & 15, fg = lane >> 4;
  const u16 NEGBF = f2bf(-1e9f);

  // ---- phase 1
  for (int rr = 0; rr < 2; rr++) {
    const int p = r0 + 2 * w + rr;
    const int rl = 2 * w + rr;
    const float* up = u + ((size_t)b * NU * NP + p) * NP + lane * 4;
    float4 uv[NU];
    #pragma unroll
    for (int uu = 0; uu < NU; uu++) uv[uu] = *(const float4*)(up + (size_t)uu * NP * NP);
    double imp[4] = {0.0, 0.0, 0.0, 0.0};
    #pragma unroll
    for (int h = 0; h < NH; h++) {
      double s0 = (double)ub[h], s1 = s0, s2 = s0, s3 = s0;
      #pragma unroll
      for (int uu = 0; uu < NU; uu++) {
        double ww = (double)uw[h * NU + uu];
        s0 += ww * (double)uv[uu].x;
        s1 += ww * (double)uv[uu].y;
        s2 += ww * (double)uv[uu].z;
        s3 += ww * (double)uv[uu].w;
      }
      imp[0] += fabs(s0); imp[1] += fabs(s1); imp[2] += fabs(s2); imp[3] += fabs(s3);
      ushort4 o;
      o.x = f2bf((float)s0); o.y = f2bf((float)s1);
      o.z = f2bf((float)s2); o.w = f2bf((float)s3);
      *(ushort4*)(bias + (h * 16 + rl) * 256 + lane * 4) = o;
    }
    u64 ib0 = (u64)__double_as_longlong(imp[0]);
    u64 ib1 = (u64)__double_as_longlong(imp[1]);
    u64 ib2 = (u64)__double_as_longlong(imp[2]);
    u64 ib3 = (u64)__double_as_longlong(imp[3]);
    u64 res = 0;
    for (int bit = 62; bit >= 0; --bit) {
      u64 cand = res | (1ull << bit);
      int cnt = __popcll(__ballot(ib0 >= cand)) + __popcll(__ballot(ib1 >= cand))
              + __popcll(__ballot(ib2 >= cand)) + __popcll(__ballot(ib3 >= cand));
      if (cnt >= 32) res = cand;
    }
    bool k0 = ib0 >= res, k1 = ib1 >= res, k2 = ib2 >= res, k3 = ib3 >= res;
    #pragma unroll
    for (int h = 0; h < NH; h++) {
      ushort4* pp = (ushort4*)(bias + (h * 16 + rl) * 256 + lane * 4);
      ushort4 v = *pp;
      if (!k0) v.x = NEGBF;
      if (!k1) v.y = NEGBF;
      if (!k2) v.z = NEGBF;
      if (!k3) v.w = NEGBF;
      *pp = v;
    }
  }
  __syncthreads();

  // ---- phase 2: wave w = head w
  const size_t bh = (size_t)b * NH + w;
  const u16* qp = qb + (bh * NP + r0) * NHD;
  short8 af = *(const short8*)(qp + fr * NHD + fg * 8);
  const u16* kp = kb + bh * NP * NHD;
  u16* ps = bias + w * 4096;                    // head-w slice: bias now, P later
  const float scale = 0.17677669529663687f;     // 1/sqrt(32)

  // pass A: row maxes
  float mx[4] = {-3e38f, -3e38f, -3e38f, -3e38f};
  #pragma unroll
  for (int nb = 0; nb < 16; nb++) {
    short8 bfr = *(const short8*)(kp + (nb * 16 + fr) * NHD + fg * 8);
    f32x4 z = {0.f, 0.f, 0.f, 0.f};
    z = __builtin_amdgcn_mfma_f32_16x16x32_bf16(af, bfr, z, 0, 0, 0);
    #pragma unroll
    for (int jj = 0; jj < 4; jj++)
      mx[jj] = fmaxf(mx[jj], z[jj] * scale + bf2f(ps[(fg * 4 + jj) * 256 + nb * 16 + fr]));
  }
  #pragma unroll
  for (int o = 1; o < 16; o <<= 1)
    #pragma unroll
    for (int jj = 0; jj < 4; jj++) mx[jj] = fmaxf(mx[jj], __shfl_xor(mx[jj], o));

  // pass B: recompute, e = exp(s-mx) written in place (same slot), sum
  float sum[4] = {0.f, 0.f, 0.f, 0.f};
  #pragma unroll
  for (int nb = 0; nb < 16; nb++) {
    short8 bfr = *(const short8*)(kp + (nb * 16 + fr) * NHD + fg * 8);
    f32x4 z = {0.f, 0.f, 0.f, 0.f};
    z = __builtin_amdgcn_mfma_f32_16x16x32_bf16(af, bfr, z, 0, 0, 0);
    #pragma unroll
    for (int jj = 0; jj < 4; jj++) {
      int idx = (fg * 4 + jj) * 256 + nb * 16 + fr;
      float e = __expf(z[jj] * scale + bf2f(ps[idx]) - mx[jj]);
      sum[jj] += e;
      ps[idx] = f2bf(e);
    }
  }
  #pragma unroll
  for (int o = 1; o < 16; o <<= 1)
    #pragma unroll
    for (int jj = 0; jj < 4; jj++) sum[jj] += __shfl_xor(sum[jj], o);
  float inv[4];
  #pragma unroll
  for (int jj = 0; jj < 4; jj++) inv[jj] = 1.f / sum[jj];

  // read all P rows (contiguous, conflict-free), coalesced f32 attn stores
  s16x4 rowv[16];
  #pragma unroll
  for (int i = 0; i < 16; i++) rowv[i] = *(const s16x4*)(ps + i * 256 + lane * 4);
  float* ab = attn + (bh * NP + r0) * NP;
  #pragma unroll
  for (int i = 0; i < 16; i++) {
    float iv = __shfl(inv[i & 3], (i >> 2) << 4);   // broadcast row i's 1/sum
    float4 o;
    o.x = bf2f((u16)rowv[i][0]) * iv;
    o.y = bf2f((u16)rowv[i][1]) * iv;
    o.z = bf2f((u16)rowv[i][2]) * iv;
    o.w = bf2f((u16)rowv[i][3]) * iv;
    *(float4*)(ab + i * NP + lane * 4) = o;        // full 1KB row per instr
  }
  // in-place reswizzle for conflict-free PV reads
  const int g = lane >> 1, sub = lane & 1;
  #pragma unroll
  for (int i = 0; i < 16; i++)
    *(s16x4*)(ps + i * 256 + ((g ^ (i & 7)) << 3) + sub * 4) = rowv[i];

  // PV (unnormalized P, inv folded into ctx)
  const u16* vp = vTb + bh * NHD * NP;
  f32x4 c0 = {0.f, 0.f, 0.f, 0.f}, c1 = {0.f, 0.f, 0.f, 0.f};
  #pragma unroll
  for (int kk = 0; kk < 8; kk++) {
    short8 pa = *(const short8*)(ps + fr * 256 + (((kk * 4 + fg) ^ (fr & 7)) << 3));
    short8 v0 = *(const short8*)(vp + fr * NP + kk * 32 + fg * 8);
    short8 v1 = *(const short8*)(vp + (16 + fr) * NP + kk * 32 + fg * 8);
    c0 = __builtin_amdgcn_mfma_f32_16x16x32_bf16(pa, v0, c0, 0, 0, 0);
    c1 = __builtin_amdgcn_mfma_f32_16x16x32_bf16(pa, v1, c1, 0, 0, 0);
  }
  #pragma unroll
  for (int jj = 0; jj < 4; jj++) {
    int prow = r0 + fg * 4 + jj;
    u16* crow = ctx + ((size_t)(b * NP + prow)) * NE + w * NHD;
    crow[fr]      = f2bf(c0[jj] * inv[jj]);
    crow[16 + fr] = f2bf(c1[jj] * inv[jj]);
  }
}

// ---------------- K6: LN2 + residual + RMSNorm ------------------------------
__global__ __launch_bounds__(256) void k_ln2rms(
    const float* __restrict__ ao, const float* __restrict__ x,
    const float* __restrict__ w, const float* __restrict__ b, const float* __restrict__ rw,
    float* __restrict__ hbuf, u16* __restrict__ hn) {
  int row = blockIdx.x * 4 + (threadIdx.x >> 6);
  int lane = threadIdx.x & 63;
  float4 v = *(const float4*)(ao + (size_t)row * NE + lane * 4);
  float s = v.x + v.y + v.z + v.w;
  #pragma unroll
  for (int o = 32; o; o >>= 1) s += __shfl_xor(s, o);
  float mean = s * (1.f / 256.f);
  float d0 = v.x - mean, d1 = v.y - mean, d2 = v.z - mean, d3 = v.w - mean;
  float q = d0*d0 + d1*d1 + d2*d2 + d3*d3;
  #pragma unroll
  for (int o = 32; o; o >>= 1) q += __shfl_xor(q, o);
  float r = rsqrtf(q * (1.f / 256.f) + 1e-5f);
  float4 xv = *(const float4*)(x + (size_t)row * NE + lane * 4);
  int c = lane * 4;
  float h0 = d0 * r * w[c+0] + b[c+0] + xv.x;
  float h1 = d1 * r * w[c+1] + b[c+1] + xv.y;
  float h2 = d2 * r * w[c+2] + b[c+2] + xv.z;
  float h3 = d3 * r * w[c+3] + b[c+3] + xv.w;
  *(float4*)(hbuf + (size_t)row * NE + c) = make_float4(h0, h1, h2, h3);
  float ss = h0*h0 + h1*h1 + h2*h2 + h3*h3;
  #pragma unroll
  for (int o = 32; o; o >>= 1) ss += __shfl_xor(ss, o);
  float rm = rsqrtf(ss * (1.f / 256.f) + 1.1920929e-07f);
  ushort4 o4;
  o4.x = f2bf(h0 * rm * rw[c+0]);
  o4.y = f2bf(h1 * rm * rw[c+1]);
  o4.z = f2bf(h2 * rm * rw[c+2]);
  o4.w = f2bf(h3 * rm * rw[c+3]);
  *(ushort4*)(hn + (size_t)row * NE + c) = o4;
}

// ---------------- launch ----------------------------------------------------
extern "C" void kernel_launch(void* const* d_in, const int* in_sizes, int n_in,
                              void* d_out, int out_size, void* d_ws, size_t ws_size,
                              hipStream_t stream) {
  (void)in_sizes; (void)n_in; (void)out_size; (void)ws_size;
  const float* x    = (const float*)d_in[0];
  const float* u    = (const float*)d_in[1];
  const float* n1w  = (const float*)d_in[2];
  const float* n1b  = (const float*)d_in[3];
  const float* wq   = (const float*)d_in[4];
  const float* wk   = (const float*)d_in[5];
  const float* wv   = (const float*)d_in[6];
  const float* wo   = (const float*)d_in[7];
  const float* bo   = (const float*)d_in[8];
  const float* uw   = (const float*)d_in[9];
  const float* ub   = (const float*)d_in[10];
  const float* n2w  = (const float*)d_in[11];
  const float* n2b  = (const float*)d_in[12];
  const float* rmsw = (const float*)d_in[13];
  const float* w1   = (const float*)d_in[14];
  const float* b1   = (const float*)d_in[15];
  const float* w2   = (const float*)d_in[16];
  const float* b2   = (const float*)d_in[17];
  float* out0 = (float*)d_out;
  float* attn = out0 + (size_t)NM * NE;   // second tuple output
  char* ws = (char*)d_ws;
  u16* wqkvT = (u16*)(ws + 0x000000);
  u16* woT   = (u16*)(ws + 0x060000);
  u16* w1T   = (u16*)(ws + 0x080000);
  u16* w2T   = (u16*)(ws + 0x100000);
  u16* qb    = (u16*)(ws + 0x200000);
  u16* kb    = (u16*)(ws + 0xA00000);
  u16* vTb   = (u16*)(ws + 0x1200000);
  u16* xn    = (u16*)(ws + 0x1A00000);
  u16* ctx   = (u16*)(ws + 0x2200000);
  float* ao  = (float*)(ws + 0x2A00000);
  float* hb  = (float*)(ws + 0x3A00000);
  u16* hn    = (u16*)(ws + 0x4A00000);
  u16* tb    = (u16*)(ws + 0x200000);     // overlaps q/k/vT/xn (dead before FFN1)

  k_prep<<<dim3(768), dim3(256), 0, stream>>>(wq, wk, wv, wo, w1, w2, wqkvT, woT, w1T, w2T);
  k_ln1<<<dim3(NM/4), dim3(256), 0, stream>>>(x, n1w, n1b, xn);
  k_gemm128<<<dim3(NM/128, 768/128), dim3(256), 0, stream>>>(xn, wqkvT, NE, EpiQKV{qb, kb, vTb});
  k_fattn<<<dim3(NB*16), dim3(512), 0, stream>>>(u, uw, ub, qb, kb, vTb, attn, ctx);
  k_gemm128<<<dim3(NM/128, NE/128), dim3(256), 0, stream>>>(ctx, woT, NE, EpiWo{bo, ao});
  k_ln2rms<<<dim3(NM/4), dim3(256), 0, stream>>>(ao, x, n2w, n2b, rmsw, hb, hn);
  k_gemm128<<<dim3(NM/128, NDFF/128), dim3(256), 0, stream>>>(hn, w1T, NE, EpiFFN1{b1, tb});
  k_gemm128<<<dim3(NM/128, NE/128), dim3(256), 0, stream>>>(tb, w2T, NDFF, EpiFFN2{b2, hb, out0});
}

// Round 8
// 403.546 us; speedup vs baseline: 1.2075x; 1.0481x over previous
//
#include <hip/hip_runtime.h>
#include <hip/hip_bf16.h>

typedef unsigned short u16;
typedef unsigned long long u64;
typedef __attribute__((ext_vector_type(8))) short short8;
typedef __attribute__((ext_vector_type(4))) short s16x4;
typedef __attribute__((ext_vector_type(4))) float f32x4;

#define NB 64
#define NP 256
#define NE 256
#define NH 8
#define NHD 32
#define NU 6
#define NDFF 1024
#define NM (NB*NP)   // 16384 tokens

__device__ __forceinline__ u16 f2bf(float f) {
  unsigned u = __float_as_uint(f);
  unsigned r = 0x7fffu + ((u >> 16) & 1u);
  return (u16)((u + r) >> 16);
}
__device__ __forceinline__ float bf2f(u16 v) {
  return __uint_as_float(((unsigned)v) << 16);
}

// async global->LDS, 16B per lane, dest = wave-uniform base + lane*16
__device__ __forceinline__ void gl_lds16(const u16* g, u16* l) {
  __builtin_amdgcn_global_load_lds(
      (const __attribute__((address_space(1))) unsigned int*)g,
      (__attribute__((address_space(3))) unsigned int*)l, 16, 0, 0);
}

// ---------------- K0: tiled transpose f32 -> bf16^T ------------------------
__global__ __launch_bounds__(256) void k_prep(
    const float* __restrict__ wq, const float* __restrict__ wk, const float* __restrict__ wv,
    const float* __restrict__ wo, const float* __restrict__ w1, const float* __restrict__ w2,
    u16* __restrict__ wqkvT, u16* __restrict__ woT, u16* __restrict__ w1T, u16* __restrict__ w2T) {
  __shared__ float tile[32][33];
  int bid = blockIdx.x;
  const float* src; u16* dst; int R, C, tr, tc;
  if (bid < 192)      { int m = bid >> 6, t = bid & 63; src = m==0?wq:(m==1?wk:wv); dst = wqkvT + m*256*256; R=256; C=256;  tr=t>>3; tc=t&7;  }
  else if (bid < 256) { int t = bid-192; src=wo; dst=woT; R=256;  C=256;  tr=t>>3; tc=t&7;  }
  else if (bid < 512) { int t = bid-256; src=w1; dst=w1T; R=256;  C=1024; tr=t>>5; tc=t&31; }
  else                { int t = bid-512; src=w2; dst=w2T; R=1024; C=256;  tr=t>>3; tc=t&7;  }
  int r0 = tr*32, c0 = tc*32;
  int rr = threadIdx.x >> 5, cc = threadIdx.x & 31;
  #pragma unroll
  for (int p = 0; p < 4; p++)
    tile[rr + p*8][cc] = src[(size_t)(r0 + rr + p*8) * C + c0 + cc];
  __syncthreads();
  #pragma unroll
  for (int p = 0; p < 4; p++)
    dst[(size_t)(c0 + rr + p*8) * R + r0 + cc] = f2bf(tile[cc][rr + p*8]);
}

// ---------------- K1: LayerNorm1 -> xn bf16 [16384][256] --------------------
__global__ __launch_bounds__(256) void k_ln1(
    const float* __restrict__ x, const float* __restrict__ w, const float* __restrict__ b,
    u16* __restrict__ xn) {
  int row = blockIdx.x * 4 + (threadIdx.x >> 6);
  int lane = threadIdx.x & 63;
  float4 v = *(const float4*)(x + (size_t)row * NE + lane * 4);
  float s = v.x + v.y + v.z + v.w;
  #pragma unroll
  for (int o = 32; o; o >>= 1) s += __shfl_xor(s, o);
  float mean = s * (1.f / 256.f);
  float d0 = v.x - mean, d1 = v.y - mean, d2 = v.z - mean, d3 = v.w - mean;
  float q = d0*d0 + d1*d1 + d2*d2 + d3*d3;
  #pragma unroll
  for (int o = 32; o; o >>= 1) q += __shfl_xor(q, o);
  float r = rsqrtf(q * (1.f / 256.f) + 1e-5f);
  int c = lane * 4;
  ushort4 o4;
  o4.x = f2bf(d0 * r * w[c+0] + b[c+0]);
  o4.y = f2bf(d1 * r * w[c+1] + b[c+1]);
  o4.z = f2bf(d2 * r * w[c+2] + b[c+2]);
  o4.w = f2bf(d3 * r * w[c+3] + b[c+3]);
  *(ushort4*)(xn + (size_t)row * NE + c) = o4;
}

// ---------------- K_GEMM: 128x128 tile, BK=32, gl_lds staging, LDS-repacked
// vectorized epilogue. C[M][N] = A[M][K] * BT[N][K]^T; epi.vec(m, n0, 8 bf16).
template<class Epi>
__global__ __launch_bounds__(256, 3) void k_gemm128(
    const u16* __restrict__ A, const u16* __restrict__ BT, int K, Epi epi) {
  __shared__ __align__(16) u16 smem[128 * 132];        // 33 KB: staging + repack
  u16* As = smem;                                      // [128][32]
  u16* Bs = smem + 4096;                               // [128][32]
  const int t = threadIdx.x;
  const int m0 = blockIdx.x * 128, n0 = blockIdx.y * 128;
  const int lane = t & 63, wv = t >> 6;
  const int fr = lane & 15, fg = lane >> 4;
  const int wm = (wv >> 1) * 64, wn = (wv & 1) * 64;
  const int row = t >> 2;
  const int gs = (t & 3) ^ ((row >> 1) & 3);          // pre-swizzled source group
  const u16* Ap = A + (size_t)(m0 + row) * K + gs * 8;
  const u16* Bp = BT + (size_t)(n0 + row) * K + gs * 8;
  u16* lA = As + wv * 512;
  u16* lB = Bs + wv * 512;
  f32x4 acc[4][4] = {};
  for (int k0 = 0; k0 < K; k0 += 32) {
    __syncthreads();
    gl_lds16(Ap + k0, lA);
    gl_lds16(Ap + k0 + (size_t)64 * K, lA + 2048);
    gl_lds16(Bp + k0, lB);
    gl_lds16(Bp + k0 + (size_t)64 * K, lB + 2048);
    __syncthreads();
    short8 a[4], b[4];
    #pragma unroll
    for (int i = 0; i < 4; i++) {
      int ra = wm + i * 16 + fr;
      a[i] = *(const short8*)(As + ra * 32 + ((fg ^ ((ra >> 1) & 3)) << 3));
    }
    #pragma unroll
    for (int j = 0; j < 4; j++) {
      int rb = wn + j * 16 + fr;
      b[j] = *(const short8*)(Bs + rb * 32 + ((fg ^ ((rb >> 1) & 3)) << 3));
    }
    #pragma unroll
    for (int i = 0; i < 4; i++)
      #pragma unroll
      for (int j = 0; j < 4; j++)
        acc[i][j] = __builtin_amdgcn_mfma_f32_16x16x32_bf16(a[i], b[j], acc[i][j], 0, 0, 0);
  }
  // repack: acc -> bf16 LDS tile [128][132]
  __syncthreads();                 // all waves done reading As/Bs
  #pragma unroll
  for (int i = 0; i < 4; i++)
    #pragma unroll
    for (int j = 0; j < 4; j++)
      #pragma unroll
      for (int jj = 0; jj < 4; jj++)
        smem[(wm + i * 16 + fg * 4 + jj) * 132 + wn + j * 16 + fr] = f2bf(acc[i][j][jj]);
  __syncthreads();
  // vectorized store: 8 rounds, each thread stores one 16B chunk
  #pragma unroll
  for (int rr = 0; rr < 8; rr++) {
    int rl = rr * 16 + (t >> 4);
    int c0 = (t & 15) * 8;
    short8 v = *(const short8*)(smem + rl * 132 + c0);
    epi.vec(m0 + rl, n0 + c0, v);
  }
}

struct EpiQK {       // N=512: q then k, row-contiguous per head
  u16 *q, *k;
  __device__ __forceinline__ void vec(int m, int n, short8 v) const {
    int b = m >> 8, p = m & 255;
    u16* dst = (n < 256)
      ? q + ((((size_t)(b*NH + (n >> 5))) * NP + p) * NHD + (n & 31))
      : k + ((((size_t)(b*NH + ((n - 256) >> 5))) * NP + p) * NHD + (n & 31));
    *(short8*)dst = v;
  }
};
struct EpiVT {       // transposed GEMM: m = v-dim (h,d), n = token (b,p)
  u16* vT;
  __device__ __forceinline__ void vec(int m, int n, short8 v) const {
    int h = m >> 5, d = m & 31, b = n >> 8, p0 = n & 255;
    *(short8*)(vT + (((size_t)(b*NH + h)) * NHD + d) * NP + p0) = v;
  }
};
struct EpiWo {
  const float* bo; float* ao;
  __device__ __forceinline__ void vec(int m, int n, short8 v) const {
    float* dst = ao + (size_t)m * NE + n;
    float4 o0, o1;
    o0.x = bf2f((u16)v[0]) + bo[n+0]; o0.y = bf2f((u16)v[1]) + bo[n+1];
    o0.z = bf2f((u16)v[2]) + bo[n+2]; o0.w = bf2f((u16)v[3]) + bo[n+3];
    o1.x = bf2f((u16)v[4]) + bo[n+4]; o1.y = bf2f((u16)v[5]) + bo[n+5];
    o1.z = bf2f((u16)v[6]) + bo[n+6]; o1.w = bf2f((u16)v[7]) + bo[n+7];
    *(float4*)dst = o0; *(float4*)(dst + 4) = o1;
  }
};
struct EpiFFN1 {
  const float* b1; u16* tb;
  __device__ __forceinline__ void vec(int m, int n, short8 v) const {
    short8 o;
    #pragma unroll
    for (int i = 0; i < 8; i++) {
      float s = bf2f((u16)v[i]) + b1[n + i];
      o[i] = (short)f2bf(s / (1.f + __expf(-s)));
    }
    *(short8*)(tb + (size_t)m * NDFF + n) = o;
  }
};
struct EpiFFN2 {
  const float* b2; const float* hb; float* out0;
  __device__ __forceinline__ void vec(int m, int n, short8 v) const {
    const float* hp = hb + (size_t)m * NE + n;
    float4 h0 = *(const float4*)hp, h1 = *(const float4*)(hp + 4);
    float4 o0, o1;
    o0.x = bf2f((u16)v[0]) + b2[n+0] + h0.x; o0.y = bf2f((u16)v[1]) + b2[n+1] + h0.y;
    o0.z = bf2f((u16)v[2]) + b2[n+2] + h0.z; o0.w = bf2f((u16)v[3]) + b2[n+3] + h0.w;
    o1.x = bf2f((u16)v[4]) + b2[n+4] + h1.x; o1.y = bf2f((u16)v[5]) + b2[n+5] + h1.y;
    o1.z = bf2f((u16)v[6]) + b2[n+6] + h1.z; o1.w = bf2f((u16)v[7]) + b2[n+7] + h1.w;
    float* dst = out0 + (size_t)m * NE + n;
    *(float4*)dst = o0; *(float4*)(dst + 4) = o1;
  }
};

// ---------------- K_FATTN: fused uh + top-32 + attention (unchanged) -------
__global__ __launch_bounds__(512, 2) void k_fattn(
    const float* __restrict__ u, const float* __restrict__ uw, const float* __restrict__ ub,
    const u16* __restrict__ qb, const u16* __restrict__ kb, const u16* __restrict__ vTb,
    float* __restrict__ attn, u16* __restrict__ ctx) {
  __shared__ __align__(16) u16 bias[NH * 16 * 256];   // 64 KB
  const int i0 = blockIdx.x;
  const int b = (i0 & 7) * 8 + ((i0 >> 3) & 7);       // all 16 tiles of b on one XCD
  const int r0 = (i0 >> 6) << 4;
  const int w = threadIdx.x >> 6;
  const int lane = threadIdx.x & 63;
  const int fr = lane & 15, fg = lane >> 4;
  const u16 NEGBF = f2bf(-1e9f);

  // ---- phase 1: uh (f64) + top-32 per row
  for (int rr = 0; rr < 2; rr++) {
    const int p = r0 + 2 * w + rr;
    const int rl = 2 * w + rr;
    const float* up = u + ((size_t)b * NU * NP + p) * NP + lane * 4;
    float4 uv[NU];
    #pragma unroll
    for (int uu = 0; uu < NU; uu++) uv[uu] = *(const float4*)(up + (size_t)uu * NP * NP);
    double imp[4] = {0.0, 0.0, 0.0, 0.0};
    #pragma unroll
    for (int h = 0; h < NH; h++) {
      double s0 = (double)ub[h], s1 = s0, s2 = s0, s3 = s0;
      #pragma unroll
      for (int uu = 0; uu < NU; uu++) {
        double ww = (double)uw[h * NU + uu];
        s0 += ww * (double)uv[uu].x;
        s1 += ww * (double)uv[uu].y;
        s2 += ww * (double)uv[uu].z;
        s3 += ww * (double)uv[uu].w;
      }
      imp[0] += fabs(s0); imp[1] += fabs(s1); imp[2] += fabs(s2); imp[3] += fabs(s3);
      ushort4 o;
      o.x = f2bf((float)s0); o.y = f2bf((float)s1);
      o.z = f2bf((float)s2); o.w = f2bf((float)s3);
      *(ushort4*)(bias + (h * 16 + rl) * 256 + lane * 4) = o;
    }
    u64 ib0 = (u64)__double_as_longlong(imp[0]);
    u64 ib1 = (u64)__double_as_longlong(imp[1]);
    u64 ib2 = (u64)__double_as_longlong(imp[2]);
    u64 ib3 = (u64)__double_as_longlong(imp[3]);
    u64 res = 0;
    for (int bit = 62; bit >= 0; --bit) {
      u64 cand = res | (1ull << bit);
      int cnt = __popcll(__ballot(ib0 >= cand)) + __popcll(__ballot(ib1 >= cand))
              + __popcll(__ballot(ib2 >= cand)) + __popcll(__ballot(ib3 >= cand));
      if (cnt >= 32) res = cand;
    }
    bool k0 = ib0 >= res, k1 = ib1 >= res, k2 = ib2 >= res, k3 = ib3 >= res;
    #pragma unroll
    for (int h = 0; h < NH; h++) {
      ushort4* pp = (ushort4*)(bias + (h * 16 + rl) * 256 + lane * 4);
      ushort4 v = *pp;
      if (!k0) v.x = NEGBF;
      if (!k1) v.y = NEGBF;
      if (!k2) v.z = NEGBF;
      if (!k3) v.w = NEGBF;
      *pp = v;
    }
  }
  __syncthreads();

  // ---- phase 2: wave w = head w
  const size_t bh = (size_t)b * NH + w;
  const u16* qp = qb + (bh * NP + r0) * NHD;
  short8 af = *(const short8*)(qp + fr * NHD + fg * 8);
  const u16* kp = kb + bh * NP * NHD;
  u16* ps = bias + w * 4096;                    // head-w slice: bias now, P later
  const float scale = 0.17677669529663687f;     // 1/sqrt(32)

  // pass A: row maxes
  float mx[4] = {-3e38f, -3e38f, -3e38f, -3e38f};
  #pragma unroll
  for (int nb = 0; nb < 16; nb++) {
    short8 bfr = *(const short8*)(kp + (nb * 16 + fr) * NHD + fg * 8);
    f32x4 z = {0.f, 0.f, 0.f, 0.f};
    z = __builtin_amdgcn_mfma_f32_16x16x32_bf16(af, bfr, z, 0, 0, 0);
    #pragma unroll
    for (int jj = 0; jj < 4; jj++)
      mx[jj] = fmaxf(mx[jj], z[jj] * scale + bf2f(ps[(fg * 4 + jj) * 256 + nb * 16 + fr]));
  }
  #pragma unroll
  for (int o = 1; o < 16; o <<= 1)
    #pragma unroll
    for (int jj = 0; jj < 4; jj++) mx[jj] = fmaxf(mx[jj], __shfl_xor(mx[jj], o));

  // pass B: recompute, e = exp(s-mx) written in place (same slot), sum
  float sum[4] = {0.f, 0.f, 0.f, 0.f};
  #pragma unroll
  for (int nb = 0; nb < 16; nb++) {
    short8 bfr = *(const short8*)(kp + (nb * 16 + fr) * NHD + fg * 8);
    f32x4 z = {0.f, 0.f, 0.f, 0.f};
    z = __builtin_amdgcn_mfma_f32_16x16x32_bf16(af, bfr, z, 0, 0, 0);
    #pragma unroll
    for (int jj = 0; jj < 4; jj++) {
      int idx = (fg * 4 + jj) * 256 + nb * 16 + fr;
      float e = __expf(z[jj] * scale + bf2f(ps[idx]) - mx[jj]);
      sum[jj] += e;
      ps[idx] = f2bf(e);
    }
  }
  #pragma unroll
  for (int o = 1; o < 16; o <<= 1)
    #pragma unroll
    for (int jj = 0; jj < 4; jj++) sum[jj] += __shfl_xor(sum[jj], o);
  float inv[4];
  #pragma unroll
  for (int jj = 0; jj < 4; jj++) inv[jj] = 1.f / sum[jj];

  // read all P rows (contiguous, conflict-free), coalesced f32 attn stores
  s16x4 rowv[16];
  #pragma unroll
  for (int i = 0; i < 16; i++) rowv[i] = *(const s16x4*)(ps + i * 256 + lane * 4);
  float* ab = attn + (bh * NP + r0) * NP;
  #pragma unroll
  for (int i = 0; i < 16; i++) {
    float iv = __shfl(inv[i & 3], (i >> 2) << 4);   // broadcast row i's 1/sum
    float4 o;
    o.x = bf2f((u16)rowv[i][0]) * iv;
    o.y = bf2f((u16)rowv[i][1]) * iv;
    o.z = bf2f((u16)rowv[i][2]) * iv;
    o.w = bf2f((u16)rowv[i][3]) * iv;
    *(float4*)(ab + i * NP + lane * 4) = o;        // full 1KB row per instr
  }
  // in-place reswizzle for conflict-free PV reads
  const int g = lane >> 1, sub = lane & 1;
  #pragma unroll
  for (int i = 0; i < 16; i++)
    *(s16x4*)(ps + i * 256 + ((g ^ (i & 7)) << 3) + sub * 4) = rowv[i];

  // PV (unnormalized P, inv folded into ctx)
  const u16* vp = vTb + bh * NHD * NP;
  f32x4 c0 = {0.f, 0.f, 0.f, 0.f}, c1 = {0.f, 0.f, 0.f, 0.f};
  #pragma unroll
  for (int kk = 0; kk < 8; kk++) {
    short8 pa = *(const short8*)(ps + fr * 256 + (((kk * 4 + fg) ^ (fr & 7)) << 3));
    short8 v0 = *(const short8*)(vp + fr * NP + kk * 32 + fg * 8);
    short8 v1 = *(const short8*)(vp + (16 + fr) * NP + kk * 32 + fg * 8);
    c0 = __builtin_amdgcn_mfma_f32_16x16x32_bf16(pa, v0, c0, 0, 0, 0);
    c1 = __builtin_amdgcn_mfma_f32_16x16x32_bf16(pa, v1, c1, 0, 0, 0);
  }
  #pragma unroll
  for (int jj = 0; jj < 4; jj++) {
    int prow = r0 + fg * 4 + jj;
    u16* crow = ctx + ((size_t)(b * NP + prow)) * NE + w * NHD;
    crow[fr]      = f2bf(c0[jj] * inv[jj]);
    crow[16 + fr] = f2bf(c1[jj] * inv[jj]);
  }
}

// ---------------- K6: LN2 + residual + RMSNorm ------------------------------
__global__ __launch_bounds__(256) void k_ln2rms(
    const float* __restrict__ ao, const float* __restrict__ x,
    const float* __restrict__ w, const float* __restrict__ b, const float* __restrict__ rw,
    float* __restrict__ hbuf, u16* __restrict__ hn) {
  int row = blockIdx.x * 4 + (threadIdx.x >> 6);
  int lane = threadIdx.x & 63;
  float4 v = *(const float4*)(ao + (size_t)row * NE + lane * 4);
  float s = v.x + v.y + v.z + v.w;
  #pragma unroll
  for (int o = 32; o; o >>= 1) s += __shfl_xor(s, o);
  float mean = s * (1.f / 256.f);
  float d0 = v.x - mean, d1 = v.y - mean, d2 = v.z - mean, d3 = v.w - mean;
  float q = d0*d0 + d1*d1 + d2*d2 + d3*d3;
  #pragma unroll
  for (int o = 32; o; o >>= 1) q += __shfl_xor(q, o);
  float r = rsqrtf(q * (1.f / 256.f) + 1e-5f);
  float4 xv = *(const float4*)(x + (size_t)row * NE + lane * 4);
  int c = lane * 4;
  float h0 = d0 * r * w[c+0] + b[c+0] + xv.x;
  float h1 = d1 * r * w[c+1] + b[c+1] + xv.y;
  float h2 = d2 * r * w[c+2] + b[c+2] + xv.z;
  float h3 = d3 * r * w[c+3] + b[c+3] + xv.w;
  *(float4*)(hbuf + (size_t)row * NE + c) = make_float4(h0, h1, h2, h3);
  float ss = h0*h0 + h1*h1 + h2*h2 + h3*h3;
  #pragma unroll
  for (int o = 32; o; o >>= 1) ss += __shfl_xor(ss, o);
  float rm = rsqrtf(ss * (1.f / 256.f) + 1.1920929e-07f);
  ushort4 o4;
  o4.x = f2bf(h0 * rm * rw[c+0]);
  o4.y = f2bf(h1 * rm * rw[c+1]);
  o4.z = f2bf(h2 * rm * rw[c+2]);
  o4.w = f2bf(h3 * rm * rw[c+3]);
  *(ushort4*)(hn + (size_t)row * NE + c) = o4;
}

// ---------------- launch ----------------------------------------------------
extern "C" void kernel_launch(void* const* d_in, const int* in_sizes, int n_in,
                              void* d_out, int out_size, void* d_ws, size_t ws_size,
                              hipStream_t stream) {
  (void)in_sizes; (void)n_in; (void)out_size; (void)ws_size;
  const float* x    = (const float*)d_in[0];
  const float* u    = (const float*)d_in[1];
  const float* n1w  = (const float*)d_in[2];
  const float* n1b  = (const float*)d_in[3];
  const float* wq   = (const float*)d_in[4];
  const float* wk   = (const float*)d_in[5];
  const float* wv   = (const float*)d_in[6];
  const float* wo   = (const float*)d_in[7];
  const float* bo   = (const float*)d_in[8];
  const float* uw   = (const float*)d_in[9];
  const float* ub   = (const float*)d_in[10];
  const float* n2w  = (const float*)d_in[11];
  const float* n2b  = (const float*)d_in[12];
  const float* rmsw = (const float*)d_in[13];
  const float* w1   = (const float*)d_in[14];
  const float* b1   = (const float*)d_in[15];
  const float* w2   = (const float*)d_in[16];
  const float* b2   = (const float*)d_in[17];
  float* out0 = (float*)d_out;
  float* attn = out0 + (size_t)NM * NE;   // second tuple output
  char* ws = (char*)d_ws;
  u16* wqkvT = (u16*)(ws + 0x000000);
  u16* woT   = (u16*)(ws + 0x060000);
  u16* w1T   = (u16*)(ws + 0x080000);
  u16* w2T   = (u16*)(ws + 0x100000);
  u16* qb    = (u16*)(ws + 0x200000);
  u16* kb    = (u16*)(ws + 0xA00000);
  u16* vTb   = (u16*)(ws + 0x1200000);
  u16* xn    = (u16*)(ws + 0x1A00000);
  u16* ctx   = (u16*)(ws + 0x2200000);
  float* ao  = (float*)(ws + 0x2A00000);
  float* hb  = (float*)(ws + 0x3A00000);
  u16* hn    = (u16*)(ws + 0x4A00000);
  u16* tb    = (u16*)(ws + 0x200000);     // overlaps q/k/vT/xn (dead before FFN1)

  k_prep<<<dim3(768), dim3(256), 0, stream>>>(wq, wk, wv, wo, w1, w2, wqkvT, woT, w1T, w2T);
  k_ln1<<<dim3(NM/4), dim3(256), 0, stream>>>(x, n1w, n1b, xn);
  k_gemm128<<<dim3(NM/128, 512/128), dim3(256), 0, stream>>>(xn, wqkvT, NE, EpiQK{qb, kb});
  k_gemm128<<<dim3(256/128, NM/128), dim3(256), 0, stream>>>(wqkvT + 512*256, xn, NE, EpiVT{vTb});
  k_fattn<<<dim3(NB*16), dim3(512), 0, stream>>>(u, uw, ub, qb, kb, vTb, attn, ctx);
  k_gemm128<<<dim3(NM/128, NE/128), dim3(256), 0, stream>>>(ctx, woT, NE, EpiWo{bo, ao});
  k_ln2rms<<<dim3(NM/4), dim3(256), 0, stream>>>(ao, x, n2w, n2b, rmsw, hb, hn);
  k_gemm128<<<dim3(NM/128, NDFF/128), dim3(256), 0, stream>>>(hn, w1T, NE, EpiFFN1{b1, tb});
  k_gemm128<<<dim3(NM/128, NE/128), dim3(256), 0, stream>>>(tb, w2T, NDFF, EpiFFN2{b2, hb, out0});
}